// Round 9
// baseline (302.667 us; speedup 1.0000x reference)
//
#include <hip/hip_runtime.h>
#include <hip/hip_bf16.h>
#include <stdint.h>

#define BATCH 4
#define SEQ   4096
#define EMB   1024
#define HD    64

typedef __bf16 bf16x8 __attribute__((ext_vector_type(8)));
typedef float  f32x4  __attribute__((ext_vector_type(4)));
typedef unsigned short u16;

union ABFrag { u16 s[8]; bf16x8 v; };

__device__ __forceinline__ u16 f2bf_rne(float f) {
    union { float f; uint32_t u; } cv; cv.f = f;
    uint32_t u = cv.u;
    return (u16)((u + 0x7fffu + ((u >> 16) & 1u)) >> 16);
}
__device__ __forceinline__ float bf2f(u16 h) {
    union { uint32_t u; float f; } cv; cv.u = ((uint32_t)h) << 16;
    return cv.f;
}
__device__ __forceinline__ void gld16(const void* g, void* l) {
    __builtin_amdgcn_global_load_lds(
        (const __attribute__((address_space(1))) void*)g,
        (__attribute__((address_space(3))) void*)l, 16, 0, 0);
}

// ---------------------------------------------------------------------------
// Kernel 1: QKV projection (wt folded in). Grid 192 = 3 weights x 64
// rowblocks, 512 threads. Each block converts+transposes its weight's fp32
// slab (1024x64) into LDS bf16 [n][k] (row stride 1032 u16), one barrier,
// then the barrier-free K-loop (R7 structure; pinned at the ws-poison
// writeback window ~42us across 4 structural variants — R4/R5/R7/R8).
// ---------------------------------------------------------------------------
__global__ __launch_bounds__(512) void qkv_kernel(
        const float* __restrict__ x,  const float* __restrict__ Wq,
        const float* __restrict__ Wk, const float* __restrict__ Wv,
        u16* __restrict__ Qw, u16* __restrict__ Kw, u16* __restrict__ Vt) {
    __shared__ u16 wl[64 * 1032];   // 129 KB: 64 rows x (1024 + 8 pad) u16

    const int t    = threadIdx.x;
    const int wave = t >> 6;        // 0..7
    const int lane = t & 63;
    const int m16  = lane & 15;
    const int quad = lane >> 4;
    const int wv   = blockIdx.x >> 6;     // weight 0..2
    const int rb   = blockIdx.x & 63;     // rowblock 0..63

    // ---- stage W slab: read fp32 W[k][n] (coalesced in n), transpose to
    // LDS bf16 wl[n][k]. 32 iters x (32 k-rows x 64 n) per block. ----
    {
        const float* Wsrc = (wv == 0) ? Wq : (wv == 1) ? Wk : Wv;
        const int kk0 = t >> 4;          // 0..31
        const int n0  = (t & 15) << 2;   // 0..60
#pragma unroll 4
        for (int it = 0; it < 32; ++it) {
            const int kk = (it << 5) + kk0;
            const float4 w4 = *(const float4*)(Wsrc + kk * HD + n0);
            wl[(n0 + 0) * 1032 + kk] = f2bf_rne(w4.x);
            wl[(n0 + 1) * 1032 + kk] = f2bf_rne(w4.y);
            wl[(n0 + 2) * 1032 + kk] = f2bf_rne(w4.z);
            wl[(n0 + 3) * 1032 + kk] = f2bf_rne(w4.w);
        }
    }
    __syncthreads();   // the ONLY barrier

    const int rtA  = (rb << 4) + (wave << 1);
    const int rowA = (rtA << 4) + m16;
    const float* xpA = x + (size_t)rowA * EMB + (quad << 3);
    const float* xpB = xpA + (16 * EMB);

    f32x4 accA[4], accB[4];
#pragma unroll
    for (int tt = 0; tt < 4; ++tt) {
        accA[tt] = (f32x4){0.f, 0.f, 0.f, 0.f};
        accB[tt] = (f32x4){0.f, 0.f, 0.f, 0.f};
    }

    const u16* wbase = &wl[m16 * 1032 + (quad << 3)];

#pragma unroll 2
    for (int kt = 0; kt < 32; ++kt) {
        const float4 a0A = *(const float4*)(xpA + (kt << 5));
        const float4 a1A = *(const float4*)(xpA + (kt << 5) + 4);
        const float4 a0B = *(const float4*)(xpB + (kt << 5));
        const float4 a1B = *(const float4*)(xpB + (kt << 5) + 4);
        ABFrag afA, afB;
        afA.s[0] = f2bf_rne(a0A.x); afA.s[1] = f2bf_rne(a0A.y);
        afA.s[2] = f2bf_rne(a0A.z); afA.s[3] = f2bf_rne(a0A.w);
        afA.s[4] = f2bf_rne(a1A.x); afA.s[5] = f2bf_rne(a1A.y);
        afA.s[6] = f2bf_rne(a1A.z); afA.s[7] = f2bf_rne(a1A.w);
        afB.s[0] = f2bf_rne(a0B.x); afB.s[1] = f2bf_rne(a0B.y);
        afB.s[2] = f2bf_rne(a0B.z); afB.s[3] = f2bf_rne(a0B.w);
        afB.s[4] = f2bf_rne(a1B.x); afB.s[5] = f2bf_rne(a1B.y);
        afB.s[6] = f2bf_rne(a1B.z); afB.s[7] = f2bf_rne(a1B.w);
#pragma unroll
        for (int tt = 0; tt < 4; ++tt) {
            const bf16x8 bf = *(const bf16x8*)(wbase + tt * (16 * 1032) + (kt << 5));
            accA[tt] = __builtin_amdgcn_mfma_f32_16x16x32_bf16(afA.v, bf, accA[tt], 0, 0, 0);
            accB[tt] = __builtin_amdgcn_mfma_f32_16x16x32_bf16(afB.v, bf, accB[tt], 0, 0, 0);
        }
    }

#pragma unroll
    for (int half = 0; half < 2; ++half) {
        const f32x4* acc = half ? accB : accA;
        const int rowbase = ((rtA + half) << 4) + (quad << 2);
        const int bidx = rowbase >> 12;
        const int t0   = rowbase & 4095;
#pragma unroll
        for (int tt = 0; tt < 4; ++tt) {
            const int col = (tt << 4) + m16;
            if (wv == 0) {
#pragma unroll
                for (int reg = 0; reg < 4; ++reg)
                    Qw[(size_t)(rowbase + reg) * HD + col] = f2bf_rne(acc[tt][reg] * 0.03125f);
            } else if (wv == 1) {
#pragma unroll
                for (int reg = 0; reg < 4; ++reg)
                    Kw[(size_t)(rowbase + reg) * HD + col] = f2bf_rne(acc[tt][reg]);
            } else {
                ushort4 vv;
                vv.x = f2bf_rne(acc[tt][0]); vv.y = f2bf_rne(acc[tt][1]);
                vv.z = f2bf_rne(acc[tt][2]); vv.w = f2bf_rne(acc[tt][3]);
                *(ushort4*)(Vt + (size_t)((bidx << 6) + col) * SEQ + t0) = vv;
            }
        }
    }
}

// ---------------------------------------------------------------------------
// Kernel 2: split-K causal flash attention + fused fan-in combine.
// Structure = R8 attn (128 q-rows, 8 waves, balanced grid 512). After the
// partial epilogue, device-scope atomic fan-in: the 4th chunk-block of each
// (b,i) combines the partials (L2/L3-hot) and writes final fp32 out.
// ---------------------------------------------------------------------------
__global__ __launch_bounds__(512) void attn_kernel(
        const u16* __restrict__ Qw, const u16* __restrict__ Kw,
        const u16* __restrict__ Vt, u16* __restrict__ Opart,
        float* __restrict__ Mp, float* __restrict__ Lp,
        int* __restrict__ counters, float* __restrict__ out) {
    __shared__ u16 kv[2][2][4096];     // [buf][K/V][64 rows x 8 chunks] = 32 KB
    __shared__ u16 ldsP[8][16 * 72];   // per-wave P[q][k], row stride 72 u16
    __shared__ int lastflag;

    const int pid = blockIdx.x;        // 0..511
    const int r   = pid >> 8;
    const int s   = pid & 255;
    const int b   = s >> 6;
    const int i0  = (s >> 1) & 31;
    const int ch  = s & 1;
    const int i   = r ? (31 - i0) : i0;       // q-tile (128 rows) 0..31
    const int c   = (ch << 1) | r;            // chunk 0..3
    const int jmax = (i << 1) + 1;            // block's last KV tile
    const int p_out = (((b << 5) + i) << 2) + c;

    const int wave = threadIdx.x >> 6;        // 0..7
    const int lane = threadIdx.x & 63;
    const int m16  = lane & 15;
    const int quad = lane >> 4;
    const int jend = (i << 1) + (wave >> 2);  // wave's last useful KV tile

    #define ISSUE_KV(buf_, jt_) do {                                           \
        const int r8_ = lane >> 3, c8_ = lane & 7;                             \
        const int kc_ = c8_ ^ r8_;                                             \
        const int row_ = (wave << 3) + r8_;             /* 0..63 */            \
        gld16(Kw + ((size_t)(b * SEQ + ((jt_) << 6) + row_) << 6) + (kc_ << 3),\
              &kv[buf_][0][wave << 9]);                                        \
        gld16(Vt + (size_t)((b << 6) + row_) * SEQ + ((jt_) << 6) + (kc_ << 3),\
              &kv[buf_][1][wave << 9]);                                        \
    } while (0)

    // Q fragment as B-operand: n = m16 = q-row, k = quad*8+j
    const int qrow = (i << 7) + (wave << 4) + m16;
    const u16* qbase = Qw + ((size_t)(b * SEQ + qrow) << 6);
    const bf16x8 qf0 = *(const bf16x8*)(qbase + (quad << 3));
    const bf16x8 qf1 = *(const bf16x8*)(qbase + 32 + (quad << 3));

    f32x4 acc[4];     // O^T: lane q = m16, d = dt*16 + quad*4 + reg
#pragma unroll
    for (int dt = 0; dt < 4; ++dt) acc[dt] = (f32x4){0.f, 0.f, 0.f, 0.f};
    float m_i = -3.0e38f;
    float l_i = 0.f;

    u16* ldsW = &ldsP[wave][0];
    const int xs0 = (quad ^ (m16 & 7)) << 3;
    const int xs1 = ((quad + 4) ^ (m16 & 7)) << 3;

    if (c <= jmax) ISSUE_KV(0, c);

    int buf = 0;
    for (int jt = c; jt <= jmax; jt += 4) {
        __syncthreads();                 // DMA of buf landed; buf^1 free
        if (jt + 4 <= jmax) ISSUE_KV(buf ^ 1, jt + 4);

        if (jt <= jend) {
            // ---- S^T = K @ Q^T : A = K-frag from LDS ----
            f32x4 sv[4];
#pragma unroll
            for (int mt = 0; mt < 4; ++mt) {
                const int base = ((mt << 4) + m16) << 6;
                bf16x8 k0 = *(const bf16x8*)&kv[buf][0][base + xs0];
                bf16x8 k1 = *(const bf16x8*)&kv[buf][0][base + xs1];
                sv[mt] = (f32x4){0.f, 0.f, 0.f, 0.f};
                sv[mt] = __builtin_amdgcn_mfma_f32_16x16x32_bf16(k0, qf0, sv[mt], 0, 0, 0);
                sv[mt] = __builtin_amdgcn_mfma_f32_16x16x32_bf16(k1, qf1, sv[mt], 0, 0, 0);
            }

            if (jt == jend) {   // diagonal tile for this wave
                const int q_in = ((wave & 3) << 4) + m16;
#pragma unroll
                for (int mt = 0; mt < 4; ++mt) {
                    const int k_in = (mt << 4) + (quad << 2);
#pragma unroll
                    for (int reg = 0; reg < 4; ++reg)
                        if (k_in + reg > q_in) sv[mt][reg] = -3.0e38f;
                }
            }

            // ---- online softmax: lane owns one q-row; 2 cross-quad hops ----
            float tm = fmaxf(fmaxf(sv[0][0], sv[0][1]), fmaxf(sv[0][2], sv[0][3]));
#pragma unroll
            for (int mt = 1; mt < 4; ++mt)
                tm = fmaxf(tm, fmaxf(fmaxf(sv[mt][0], sv[mt][1]), fmaxf(sv[mt][2], sv[mt][3])));
            tm = fmaxf(tm, __shfl_xor(tm, 16));
            tm = fmaxf(tm, __shfl_xor(tm, 32));

            const float mnew  = fmaxf(m_i, tm);
            const float alpha = __expf(m_i - mnew);
            m_i = mnew;

            float psum = 0.f;
#pragma unroll
            for (int mt = 0; mt < 4; ++mt) {
                const float p0 = __expf(sv[mt][0] - mnew);
                const float p1 = __expf(sv[mt][1] - mnew);
                const float p2 = __expf(sv[mt][2] - mnew);
                const float p3 = __expf(sv[mt][3] - mnew);
                psum += (p0 + p1) + (p2 + p3);
                ushort4 pv;
                pv.x = f2bf_rne(p0); pv.y = f2bf_rne(p1);
                pv.z = f2bf_rne(p2); pv.w = f2bf_rne(p3);
                *(ushort4*)(ldsW + m16 * 72 + (mt << 4) + (quad << 2)) = pv;
            }
            l_i = l_i * alpha + psum;
#pragma unroll
            for (int dt = 0; dt < 4; ++dt)
#pragma unroll
                for (int reg = 0; reg < 4; ++reg) acc[dt][reg] *= alpha;

            // ---- O^T += V^T @ P^T : A = V-frag from LDS ----
            const bf16x8 p0 = *(const bf16x8*)(ldsW + m16 * 72 + (quad << 3));
            const bf16x8 p1 = *(const bf16x8*)(ldsW + m16 * 72 + 32 + (quad << 3));
#pragma unroll
            for (int dt = 0; dt < 4; ++dt) {
                const int base = ((dt << 4) + m16) << 6;
                bf16x8 v0 = *(const bf16x8*)&kv[buf][1][base + xs0];
                bf16x8 v1 = *(const bf16x8*)&kv[buf][1][base + xs1];
                acc[dt] = __builtin_amdgcn_mfma_f32_16x16x32_bf16(v0, p0, acc[dt], 0, 0, 0);
                acc[dt] = __builtin_amdgcn_mfma_f32_16x16x32_bf16(v1, p1, acc[dt], 0, 0, 0);
            }
        }
        buf ^= 1;
    }
    #undef ISSUE_KV

    float l = l_i;
    l += __shfl_xor(l, 16);
    l += __shfl_xor(l, 32);

    u16* ob = Opart + ((size_t)p_out << 13);      // 128 rows x 64 d
    const int qin = (wave << 4) + m16;            // 0..127
#pragma unroll
    for (int dt = 0; dt < 4; ++dt) {
        ushort4 vv;
        vv.x = f2bf_rne(acc[dt][0]); vv.y = f2bf_rne(acc[dt][1]);
        vv.z = f2bf_rne(acc[dt][2]); vv.w = f2bf_rne(acc[dt][3]);
        *(ushort4*)(ob + qin * 64 + (dt << 4) + (quad << 2)) = vv;
    }
    if (quad == 0) {
        Mp[(p_out << 7) + qin] = m_i;
        Lp[(p_out << 7) + qin] = l;
    }

    // ---- fan-in: 4th arriver for (b,i) combines and writes final out ----
    __threadfence();                                  // device-scope release
    if (threadIdx.x == 0) {
        lastflag = (__hip_atomic_fetch_add(&counters[(b << 5) + i], 1,
                        __ATOMIC_ACQ_REL, __HIP_MEMORY_SCOPE_AGENT) == 3);
    }
    __syncthreads();
    if (lastflag) {
        const int pb  = ((b << 5) + i) << 2;
        const int row = threadIdx.x & 127;            // 0..127
        const int g4  = (threadIdx.x >> 7) << 4;      // col base 0/16/32/48
        float ms[4], lsv[4];
        float M = -3.0e38f;
#pragma unroll
        for (int cc = 0; cc < 4; ++cc) {
            ms[cc]  = Mp[((pb + cc) << 7) + row];
            lsv[cc] = Lp[((pb + cc) << 7) + row];
            M = fmaxf(M, ms[cc]);
        }
        float num[16];
#pragma unroll
        for (int v = 0; v < 16; ++v) num[v] = 0.f;
        float den = 0.f;
#pragma unroll
        for (int cc = 0; cc < 4; ++cc) {
            const float w = __expf(ms[cc] - M);
            den += w * lsv[cc];
            const u16* op = Opart + ((size_t)(pb + cc) << 13) + row * 64 + g4;
#pragma unroll
            for (int v = 0; v < 4; ++v) {
                const ushort4 o4 = *(const ushort4*)(op + (v << 2));
                num[v * 4 + 0] += w * bf2f(o4.x);
                num[v * 4 + 1] += w * bf2f(o4.y);
                num[v * 4 + 2] += w * bf2f(o4.z);
                num[v * 4 + 3] += w * bf2f(o4.w);
            }
        }
        const float rd = 1.0f / den;
        float* obp = out + ((size_t)(b * SEQ + (i << 7) + row) << 6) + g4;
#pragma unroll
        for (int v = 0; v < 4; ++v) {
            float4 o;
            o.x = num[v * 4 + 0] * rd; o.y = num[v * 4 + 1] * rd;
            o.z = num[v * 4 + 2] * rd; o.w = num[v * 4 + 3] * rd;
            *(float4*)(obp + (v << 2)) = o;
        }
    }
}

// ---------------------------------------------------------------------------
extern "C" void kernel_launch(void* const* d_in, const int* in_sizes, int n_in,
                              void* d_out, int out_size, void* d_ws, size_t ws_size,
                              hipStream_t stream) {
    const float* x  = (const float*)d_in[0];
    const float* Wq = (const float*)d_in[1];
    const float* Wk = (const float*)d_in[2];
    const float* Wv = (const float*)d_in[3];
    float* out = (float*)d_out;

    char* ws = (char*)d_ws;
    u16* Qw     = (u16*)(ws);                        // 2 MB
    u16* Kw     = (u16*)(ws + (2u << 20));           // 2 MB
    u16* Vt     = (u16*)(ws + (4u << 20));           // 2 MB  [b][64][T]
    u16* Opart  = (u16*)(ws + (13u << 19));          // 8 MB @ 6.5 MB
    float* Mp   = (float*)(ws + (29u << 19));        // 256 KB @ 14.5 MB
    float* Lp   = (float*)(ws + (59u << 18));        // 256 KB @ 14.75 MB
    int* counters = (int*)(ws + (15u << 20));        // 512 B @ 15 MB

    hipMemsetAsync(counters, 0, 128 * sizeof(int), stream);
    qkv_kernel<<<192, 512, 0, stream>>>(x, Wq, Wk, Wv, Qw, Kw, Vt);
    attn_kernel<<<512, 512, 0, stream>>>(Qw, Kw, Vt, Opart, Mp, Lp, counters, out);
}